// Round 6
// baseline (301.961 us; speedup 1.0000x reference)
//
#include <hip/hip_runtime.h>
#include <hip/hip_bf16.h>

#define AS1 __attribute__((address_space(1)))
#define AS3 __attribute__((address_space(3)))

typedef __attribute__((ext_vector_type(8))) short bfrag8;   // 8 bf16 in 4 VGPRs
typedef __attribute__((ext_vector_type(4))) float floatx4;  // MFMA accumulator

static constexpr int M = 4096, N = 4096, K = 4096;
static constexpr long long NELEM = 16777216LL;   // 4096*4096 (both x and W)
static constexpr int PB = 1024;                  // prep blocks per array

// ---------- round-to-nearest-even fp32 -> bf16 ----------
__device__ __forceinline__ unsigned short f2bf(float f) {
    unsigned int u = __float_as_uint(f);
    u += 0x7FFFu + ((u >> 16) & 1u);
    return (unsigned short)(u >> 16);
}

// ---------- ternary quantize: bf16 {-1,0,+1}; exact fp32 division as reference ----------
__device__ __forceinline__ unsigned short tq(float v, float scale_f) {
    float wn = v / scale_f;
    if (fabsf(wn) > 0.5f)
        return (unsigned short)(0x3F80u | ((__float_as_uint(v) >> 16) & 0x8000u));
    return 0;
}

// ---------- block reduce (double) -> value on thread 0 ----------
__device__ __forceinline__ double block_reduce(double s) {
    #pragma unroll
    for (int off = 32; off > 0; off >>= 1) s += __shfl_down(s, off, 64);
    __shared__ double part[4];
    int lane = threadIdx.x & 63, wv = threadIdx.x >> 6;
    if (lane == 0) part[wv] = s;
    __syncthreads();
    return part[0] + part[1] + part[2] + part[3];
}

// ---------- dual block reduce (double), broadcast result to ALL threads ----------
__device__ __forceinline__ void block_reduce2_bcast(double& a, double& b) {
    #pragma unroll
    for (int off = 32; off > 0; off >>= 1) {
        a += __shfl_down(a, off, 64);
        b += __shfl_down(b, off, 64);
    }
    __shared__ double pa[4], pb[4];
    int lane = threadIdx.x & 63, wv = threadIdx.x >> 6;
    if (lane == 0) { pa[wv] = a; pb[wv] = b; }
    __syncthreads();
    a = pa[0] + pa[1] + pa[2] + pa[3];
    b = pb[0] + pb[1] + pb[2] + pb[3];
}

// ---------- prep (R2-proven): blocks [0,PB) -> sum|x| + x->bf16 ; [PB,2PB) -> sum|w| ----------
__global__ __launch_bounds__(256) void prep_reduce(
        const float* __restrict__ x, unsigned short* __restrict__ xb,
        const float* __restrict__ w,
        double* __restrict__ px, double* __restrict__ pw) {
    const int b = blockIdx.x;
    const bool isW = b >= PB;
    const int rb = isW ? b - PB : b;
    const float4* src = (const float4*)(isW ? w : x);
    const long long base = (long long)rb * 4096 + threadIdx.x;  // float4 index

    float4 v[16];
    #pragma unroll
    for (int i = 0; i < 16; i++) v[i] = src[base + i * 256];    // 16 independent loads

    double s = 0.0;
    #pragma unroll
    for (int i = 0; i < 16; i++) {
        s += (double)fabsf(v[i].x); s += (double)fabsf(v[i].y);
        s += (double)fabsf(v[i].z); s += (double)fabsf(v[i].w);
    }

    if (!isW) {
        ushort4* xb4 = (ushort4*)xb;
        #pragma unroll
        for (int i = 0; i < 16; i++) {
            ushort4 r;
            r.x = f2bf(v[i].x); r.y = f2bf(v[i].y);
            r.z = f2bf(v[i].z); r.w = f2bf(v[i].w);
            xb4[base + i * 256] = r;
        }
    }

    double bs = block_reduce(s);
    if (threadIdx.x == 0) (isW ? pw : px)[rb] = bs;
}

// ---------- quantize w (R2-proven) + inline scale finalize ----------
__global__ __launch_bounds__(256) void quantize_w(
        const float* __restrict__ w, unsigned short* __restrict__ qb,
        const double* __restrict__ px, const double* __restrict__ pw,
        float* __restrict__ scales) {
    const int t = threadIdx.x;
    double sx = 0.0, sw = 0.0;
    #pragma unroll
    for (int i = 0; i < 4; i++) { sx += px[t + i * 256]; sw += pw[t + i * 256]; }
    block_reduce2_bcast(sx, sw);
    const float scale_w = (float)fmax(sw / (double)NELEM, 1e-8);
    const float scale_x = (float)fmax(sx / (double)NELEM, 1e-8);
    if (blockIdx.x == 0 && t == 0) { scales[0] = scale_w; scales[1] = scale_x; }

    const float4* w4 = (const float4*)w;
    ushort4* q4 = (ushort4*)qb;
    const long long base = (long long)blockIdx.x * 4096 + t;
    float4 v[16];
    #pragma unroll
    for (int i = 0; i < 16; i++) v[i] = w4[base + i * 256];
    #pragma unroll
    for (int i = 0; i < 16; i++) {
        ushort4 r;
        r.x = tq(v[i].x, scale_w); r.y = tq(v[i].y, scale_w);
        r.z = tq(v[i].z, scale_w); r.w = tq(v[i].w, scale_w);
        q4[base + i * 256] = r;
    }
}

// ---------- R11 GEMM: R7 phase skeleton + triple-buffered A = 4-half-tile-deep pipeline ----
// R7 (119.5us/MfmaUtil 50%): q3's vmcnt(4) retires A(t+1).h1 issued only ~2 phases earlier
// (<HBM latency) -> per-tile wait stall. R11 keeps R7's phases EXACTLY (same reads, 1 stage
// per phase, 2 barriers, 16 MFMA) but stages A at distance 2 into a THIRD A region:
//   LDS = A0,A1,A2 (32K each) + B0,B1 (32K each) = 160 KiB (full CU LDS; occupancy already
//   1 block/CU so no loss). Tile t: A from A[t%3], B from B[t%2].
//   q0: A(t+2).h0 -> A[(t+2)%3]  (region holds A(t-1), reads lgkm0'd at t-1 + barriers: safe)
//   q1: A(t+2).h1 ; q2: B(t+2).h0 -> B[t%2] (its reads lgkm0'd at this tile's q0: R7-safe)
//   q3: B(t+2).h1 ; MFMA ; vmcnt(8) ; barrier
// At q3: 16 loads outstanding; vmcnt(8) retires exactly {A(t+1), B(t+1)} aged 4.5-7.5
// phases (~1300-2100cy >> 900cy HBM) and keeps {A(t+2), B(t+2)} = 4 half-tiles in flight
// (deeper than m201's 3). Wait cost -> ~0. Buffer cycle period 6, unrolled compile-time.
// Tail: t=62 drains vmcnt(0) once; t=63 computes only. Fragments and per-acc k-order
// identical to R7 -> bitwise-same output.
__global__ __launch_bounds__(512, 2) void gemm_bt256(
        const unsigned short* __restrict__ A,
        const unsigned short* __restrict__ B,
        const float* __restrict__ bias,
        const float* __restrict__ scales,   // [0]=wscale, [1]=iscale
        float* __restrict__ out) {
    __shared__ alignas(16) char lds[163840];

    const int tid = threadIdx.x;
    const int lane = tid & 63;
    const int wv = tid >> 6;            // 0..7
    const int wm = wv & 1;              // 2 M-waves (128 rows each)
    const int wn = wv >> 1;             // 4 N-waves (64 cols each)
    const int col16 = lane & 15;
    const int quad  = lane >> 4;

    const int bid = blockIdx.x;
    const int swz = (bid & 7) * 32 + (bid >> 3);
    const int bx = swz & 15;            // n-tile
    const int by = swz >> 4;            // m-tile
    const int m0 = by * 256;
    const int n0 = bx * 256;

    const int srow8  = lane >> 3;            // row within 8-row group
    const int schunk = (lane & 7) ^ srow8;   // k-chunk this lane fetches
    const int scol   = schunk * 8;           // element offset

    floatx4 acc[8][4];
    #pragma unroll
    for (int i = 0; i < 8; i++)
        #pragma unroll
        for (int j = 0; j < 4; j++)
            acc[i][j] = (floatx4)0.0f;

    char* const A0 = (char*)lds;
    char* const A1 = (char*)lds + 32768;
    char* const A2 = (char*)lds + 65536;
    char* const B0 = (char*)lds + 98304;
    char* const B1 = (char*)lds + 131072;

    // stage one half-tile (128 rows x 64 k): 2 global_load_lds per thread
    auto stage_half = [&](const unsigned short* __restrict__ gmat, int base0,
                          char* region, long long k0, int h) {
        #pragma unroll
        for (int l = 0; l < 2; ++l) {
            const int c = wv * 2 + l;                       // 0..15 within half
            const unsigned short* g = gmat
                + (size_t)(base0 + h * 128 + c * 8 + srow8) * (size_t)K
                + (size_t)k0 + scol;
            char* d = region + h * 16384 + c * 1024 + lane * 16;
            __builtin_amdgcn_global_load_lds((const AS1 void*)g, (AS3 void*)d, 16, 0, 0);
        }
    };

    // ---- prologue: A(0)->A0, B(0)->B0, A(1)->A1, B(1)->B1; retire {A(0),B(0)} ----
    stage_half(A, m0, A0, 0,  0);
    stage_half(A, m0, A0, 0,  1);
    stage_half(B, n0, B0, 0,  0);
    stage_half(B, n0, B0, 0,  1);
    stage_half(A, m0, A1, 64, 0);
    stage_half(A, m0, A1, 64, 1);
    stage_half(B, n0, B1, 64, 0);
    stage_half(B, n0, B1, 64, 1);
    asm volatile("s_waitcnt vmcnt(8)" ::: "memory");
    __builtin_amdgcn_s_barrier();

    // wait_mode: 0 = vmcnt(8), 1 = vmcnt(0) [t==62], 2 = none [t==63]
    auto tile_body = [&](char* bA, char* bB, char* aT, int t, bool st, int wait_mode) {
        const long long kN = (long long)(t + 2) * 64;

        // B fragments for the whole tile (8 x ds_read_b128), held in regs
        bfrag8 bf[4][2];
        #pragma unroll
        for (int j = 0; j < 4; ++j) {
            const int rB = wn * 64 + j * 16 + col16;
            #pragma unroll
            for (int kk = 0; kk < 2; ++kk)
                bf[j][kk] = *(const bfrag8*)(bB + rB * 128 +
                                (((kk * 4 + quad) ^ (col16 & 7)) << 4));
        }

        #pragma unroll
        for (int q = 0; q < 4; ++q) {
            bfrag8 af[2][2];
            #pragma unroll
            for (int di = 0; di < 2; ++di) {
                const int rA = wm * 128 + (q * 2 + di) * 16 + col16;
                #pragma unroll
                for (int kk = 0; kk < 2; ++kk)
                    af[di][kk] = *(const bfrag8*)(bA + rA * 128 +
                                    (((kk * 4 + quad) ^ (col16 & 7)) << 4));
            }
            // distance-2 staging: A into 3rd buffer (q0/q1), B into own region (q2/q3)
            if (q == 0 && st) stage_half(A, m0, aT, kN, 0);
            if (q == 1 && st) stage_half(A, m0, aT, kN, 1);
            if (q == 2 && st) stage_half(B, n0, bB, kN, 0);
            if (q == 3 && st) stage_half(B, n0, bB, kN, 1);

            __builtin_amdgcn_s_barrier();
            asm volatile("s_waitcnt lgkmcnt(0)" ::: "memory");
            __builtin_amdgcn_s_setprio(1);
            #pragma unroll
            for (int di = 0; di < 2; ++di)
                #pragma unroll
                for (int j = 0; j < 4; ++j) {
                    acc[q * 2 + di][j] = __builtin_amdgcn_mfma_f32_16x16x32_bf16(
                        af[di][0], bf[j][0], acc[q * 2 + di][j], 0, 0, 0);
                    acc[q * 2 + di][j] = __builtin_amdgcn_mfma_f32_16x16x32_bf16(
                        af[di][1], bf[j][1], acc[q * 2 + di][j], 0, 0, 0);
                }
            __builtin_amdgcn_s_setprio(0);
            if (q == 3) {
                if (wait_mode == 0)      asm volatile("s_waitcnt vmcnt(8)" ::: "memory");
                else if (wait_mode == 1) asm volatile("s_waitcnt vmcnt(0)" ::: "memory");
            }
            __builtin_amdgcn_s_barrier();
        }
    };

    // ---- main loop: buffer pattern period 6 (A: %3, B: %2), 10 sextets = tiles 0..59 ----
    for (int t6 = 0; t6 < 10; ++t6) {
        const int tb = t6 * 6;
        tile_body(A0, B0, A2, tb + 0, true, 0);
        tile_body(A1, B1, A0, tb + 1, true, 0);
        tile_body(A2, B0, A1, tb + 2, true, 0);
        tile_body(A0, B1, A2, tb + 3, true, 0);
        tile_body(A1, B0, A0, tb + 4, true, 0);
        tile_body(A2, B1, A1, tb + 5, true, 0);
    }
    // ---- tail: tiles 60..63 ----
    tile_body(A0, B0, A2, 60, true,  0);
    tile_body(A1, B1, A0, 61, true,  0);
    tile_body(A2, B0, A1, 62, false, 1);   // drain: all remaining loads must land
    tile_body(A0, B1, A2, 63, false, 2);   // compute only

    // ---- epilogue ----
    const float wscale = scales[0];
    const float iscale = scales[1];

    float bv[4];
    #pragma unroll
    for (int j = 0; j < 4; ++j)
        bv[j] = bias[n0 + wn * 64 + j * 16 + col16] * iscale;

    #pragma unroll
    for (int i = 0; i < 8; ++i) {
        const int mbase = m0 + wm * 128 + i * 16 + quad * 4;
        #pragma unroll
        for (int j = 0; j < 4; ++j) {
            const int n = n0 + wn * 64 + j * 16 + col16;
            #pragma unroll
            for (int r = 0; r < 4; ++r)
                out[(size_t)(mbase + r) * N + n] = acc[i][j][r] * wscale + bv[j];
        }
    }
}

extern "C" void kernel_launch(void* const* d_in, const int* in_sizes, int n_in,
                              void* d_out, int out_size, void* d_ws, size_t ws_size,
                              hipStream_t stream) {
    const float* x    = (const float*)d_in[0];   // (2,2048,4096) fp32
    const float* w    = (const float*)d_in[1];   // (4096,4096) fp32
    const float* bias = (const float*)d_in[2];   // (4096,) fp32
    float* out = (float*)d_out;                  // (2,2048,4096) fp32

    char* ws = (char*)d_ws;
    float*  scales = (float*)ws;                       // 16 B
    double* px     = (double*)(ws + 256);              // 1024 doubles (8 KB)
    double* pw     = (double*)(ws + 256 + PB * 8);     // 1024 doubles (8 KB)
    unsigned short* xb = (unsigned short*)(ws + 16640);                      // 32 MB bf16 x
    unsigned short* qb = (unsigned short*)(ws + 16640 + (size_t)NELEM * 2);  // 32 MB bf16 qW

    prep_reduce<<<2 * PB, 256, 0, stream>>>(x, xb, w, px, pw);
    quantize_w<<<PB, 256, 0, stream>>>(w, qb, px, pw, scales);

    gemm_bt256<<<dim3(256), 512, 0, stream>>>(xb, qb, bias, scales, out);
}

// Round 7
// 287.741 us; speedup vs baseline: 1.0494x; 1.0494x over previous
//
#include <hip/hip_runtime.h>
#include <hip/hip_bf16.h>

#define AS1 __attribute__((address_space(1)))
#define AS3 __attribute__((address_space(3)))

typedef __attribute__((ext_vector_type(8))) short bfrag8;   // 8 bf16 in 4 VGPRs
typedef __attribute__((ext_vector_type(4))) float floatx4;  // MFMA accumulator

static constexpr int M = 4096, N = 4096, K = 4096;
static constexpr long long NELEM = 16777216LL;   // 4096*4096 (both x and W)
static constexpr int PB = 1024;                  // prep blocks per array

// ---------- round-to-nearest-even fp32 -> bf16 ----------
__device__ __forceinline__ unsigned short f2bf(float f) {
    unsigned int u = __float_as_uint(f);
    u += 0x7FFFu + ((u >> 16) & 1u);
    return (unsigned short)(u >> 16);
}

// ---------- ternary quantize: bf16 {-1,0,+1}; exact fp32 division as reference ----------
__device__ __forceinline__ unsigned short tq(float v, float scale_f) {
    float wn = v / scale_f;
    if (fabsf(wn) > 0.5f)
        return (unsigned short)(0x3F80u | ((__float_as_uint(v) >> 16) & 0x8000u));
    return 0;
}

// ---------- block reduce (double) -> value on thread 0 ----------
__device__ __forceinline__ double block_reduce(double s) {
    #pragma unroll
    for (int off = 32; off > 0; off >>= 1) s += __shfl_down(s, off, 64);
    __shared__ double part[4];
    int lane = threadIdx.x & 63, wv = threadIdx.x >> 6;
    if (lane == 0) part[wv] = s;
    __syncthreads();
    return part[0] + part[1] + part[2] + part[3];
}

// ---------- dual block reduce (double), broadcast result to ALL threads ----------
__device__ __forceinline__ void block_reduce2_bcast(double& a, double& b) {
    #pragma unroll
    for (int off = 32; off > 0; off >>= 1) {
        a += __shfl_down(a, off, 64);
        b += __shfl_down(b, off, 64);
    }
    __shared__ double pa[4], pb[4];
    int lane = threadIdx.x & 63, wv = threadIdx.x >> 6;
    if (lane == 0) { pa[wv] = a; pb[wv] = b; }
    __syncthreads();
    a = pa[0] + pa[1] + pa[2] + pa[3];
    b = pb[0] + pb[1] + pb[2] + pb[3];
}

// ---------- prep (R2-proven): blocks [0,PB) -> sum|x| + x->bf16 ; [PB,2PB) -> sum|w| ----------
__global__ __launch_bounds__(256) void prep_reduce(
        const float* __restrict__ x, unsigned short* __restrict__ xb,
        const float* __restrict__ w,
        double* __restrict__ px, double* __restrict__ pw) {
    const int b = blockIdx.x;
    const bool isW = b >= PB;
    const int rb = isW ? b - PB : b;
    const float4* src = (const float4*)(isW ? w : x);
    const long long base = (long long)rb * 4096 + threadIdx.x;  // float4 index

    float4 v[16];
    #pragma unroll
    for (int i = 0; i < 16; i++) v[i] = src[base + i * 256];    // 16 independent loads

    double s = 0.0;
    #pragma unroll
    for (int i = 0; i < 16; i++) {
        s += (double)fabsf(v[i].x); s += (double)fabsf(v[i].y);
        s += (double)fabsf(v[i].z); s += (double)fabsf(v[i].w);
    }

    if (!isW) {
        ushort4* xb4 = (ushort4*)xb;
        #pragma unroll
        for (int i = 0; i < 16; i++) {
            ushort4 r;
            r.x = f2bf(v[i].x); r.y = f2bf(v[i].y);
            r.z = f2bf(v[i].z); r.w = f2bf(v[i].w);
            xb4[base + i * 256] = r;
        }
    }

    double bs = block_reduce(s);
    if (threadIdx.x == 0) (isW ? pw : px)[rb] = bs;
}

// ---------- quantize w (R2-proven) + inline scale finalize ----------
__global__ __launch_bounds__(256) void quantize_w(
        const float* __restrict__ w, unsigned short* __restrict__ qb,
        const double* __restrict__ px, const double* __restrict__ pw,
        float* __restrict__ scales) {
    const int t = threadIdx.x;
    double sx = 0.0, sw = 0.0;
    #pragma unroll
    for (int i = 0; i < 4; i++) { sx += px[t + i * 256]; sw += pw[t + i * 256]; }
    block_reduce2_bcast(sx, sw);
    const float scale_w = (float)fmax(sw / (double)NELEM, 1e-8);
    const float scale_x = (float)fmax(sx / (double)NELEM, 1e-8);
    if (blockIdx.x == 0 && t == 0) { scales[0] = scale_w; scales[1] = scale_x; }

    const float4* w4 = (const float4*)w;
    ushort4* q4 = (ushort4*)qb;
    const long long base = (long long)blockIdx.x * 4096 + t;
    float4 v[16];
    #pragma unroll
    for (int i = 0; i < 16; i++) v[i] = w4[base + i * 256];
    #pragma unroll
    for (int i = 0; i < 16; i++) {
        ushort4 r;
        r.x = tq(v[i].x, scale_w); r.y = tq(v[i].y, scale_w);
        r.z = tq(v[i].z, scale_w); r.w = tq(v[i].w, scale_w);
        q4[base + i * 256] = r;
    }
}

// ---------- R12 GEMM: R7 skeleton + BALANCED per-phase LDS reads (8/8/4/4) ----------
// R7 (119.5us/MfmaUtil 50%) lumps 12 ds_reads into q0 (1152cy LDS in one phase vs
// ~620cy MFMA) while q1-q3 have 4 -> barrier lockstep forfeits pipe overlap. R11/R10
// proved vmcnt age is NOT the stall. R12 regroups by k-chunk, same skeleton:
//   p0: read bf[*][kk0] (4) + af[rows0-3][kk0] (4); stage A(t+1).h0; MFMA rows0-3 x kk0
//   p1: read bf[*][kk1] (4) + af[rows0-3][kk1] (4); stage A(t+1).h1; MFMA rows0-3 x kk1
//   p2: read af[rows4-7][kk0] (4);                  stage B(t+2).h0; MFMA rows4-7 x kk0
//   p3: read af[rows4-7][kk1] (4);                  stage B(t+2).h1; MFMA rows4-7 x kk1
//       then vmcnt(4) (retires B(t+1)+A(t+1), keeps B(t+2)); barrier
// Per-acc-element k-order still kk0-then-kk1 -> bitwise-identical output. Safety: all
// bufc.B reads complete at p1's lgkm0 before B-stages (p2/p3) issue — same as R7.
// Tail fixed (R7 latent race): t==62 drains vmcnt(0) so tile63's A is guaranteed.
__global__ __launch_bounds__(512, 2) void gemm_bt256(
        const unsigned short* __restrict__ A,
        const unsigned short* __restrict__ B,
        const float* __restrict__ bias,
        const float* __restrict__ scales,   // [0]=wscale, [1]=iscale
        float* __restrict__ out) {
    __shared__ alignas(16) char lds[131072];

    const int tid = threadIdx.x;
    const int lane = tid & 63;
    const int wv = tid >> 6;            // 0..7
    const int wm = wv & 1;              // 2 M-waves (128 rows each)
    const int wn = wv >> 1;             // 4 N-waves (64 cols each)
    const int col16 = lane & 15;
    const int quad  = lane >> 4;

    const int bid = blockIdx.x;
    const int swz = (bid & 7) * 32 + (bid >> 3);
    const int bx = swz & 15;            // n-tile
    const int by = swz >> 4;            // m-tile
    const int m0 = by * 256;
    const int n0 = bx * 256;

    const int srow8  = lane >> 3;            // row within 8-row group
    const int schunk = (lane & 7) ^ srow8;   // k-chunk this lane fetches
    const int scol   = schunk * 8;           // element offset

    floatx4 acc[8][4];
    #pragma unroll
    for (int i = 0; i < 8; i++)
        #pragma unroll
        for (int j = 0; j < 4; j++)
            acc[i][j] = (floatx4)0.0f;

    char* buf0 = (char*)lds;
    char* buf1 = (char*)lds + 65536;

    // stage one half-tile (128 rows x 64 k): 2 global_load_lds per thread
    auto stage_half = [&](const unsigned short* __restrict__ gmat, int base0,
                          char* region, long long k0, int h) {
        #pragma unroll
        for (int l = 0; l < 2; ++l) {
            const int c = wv * 2 + l;                       // 0..15 within half
            const unsigned short* g = gmat
                + (size_t)(base0 + h * 128 + c * 8 + srow8) * (size_t)K
                + (size_t)k0 + scol;
            char* d = region + h * 16384 + c * 1024 + lane * 16;
            __builtin_amdgcn_global_load_lds((const AS1 void*)g, (AS3 void*)d, 16, 0, 0);
        }
    };

    // ---- prologue: tile0 (4 halves) + B(1) (2 halves); keep B(1) 4 in flight ----
    stage_half(B, n0, buf0 + 32768, 0, 0);
    stage_half(B, n0, buf0 + 32768, 0, 1);
    stage_half(A, m0, buf0,         0, 0);
    stage_half(A, m0, buf0,         0, 1);
    stage_half(B, n0, buf1 + 32768, 64, 0);
    stage_half(B, n0, buf1 + 32768, 64, 1);
    asm volatile("s_waitcnt vmcnt(4)" ::: "memory");
    __builtin_amdgcn_s_barrier();

    auto tile_body = [&](char* bufc, char* bufn, int t) {
        const bool stA = (t + 1) < 64;
        const bool stB = (t + 2) < 64;
        const long long kA = (long long)(t + 1) * 64;
        const long long kB = (long long)(t + 2) * 64;
        const char* bA = bufc;
        const char* bB = bufc + 32768;

        bfrag8 bf[4][2];   // held across the whole tile
        bfrag8 af[4];      // current row-group, current kk

        // phase layout: (rg, kk) = (0,0) (0,1) (1,0) (1,1); rg0 = rows0-3, rg1 = rows4-7
        #pragma unroll
        for (int p = 0; p < 4; ++p) {
            const int rg = p >> 1;         // row group: 0 -> rows 0..3, 1 -> rows 4..7
            const int kk = p & 1;          // k-chunk

            // ds reads for this phase
            if (rg == 0) {                 // p0/p1: also read bf[*][kk] (4 reads)
                #pragma unroll
                for (int j = 0; j < 4; ++j) {
                    const int rB = wn * 64 + j * 16 + col16;
                    bf[j][kk] = *(const bfrag8*)(bB + rB * 128 +
                                    (((kk * 4 + quad) ^ (col16 & 7)) << 4));
                }
            }
            #pragma unroll
            for (int r = 0; r < 4; ++r) {  // af rows rg*4 .. rg*4+3, chunk kk (4 reads)
                const int rA = wm * 128 + (rg * 4 + r) * 16 + col16;
                af[r] = *(const bfrag8*)(bA + rA * 128 +
                                (((kk * 4 + quad) ^ (col16 & 7)) << 4));
            }

            // staging slots (R7 map): p0 A.h0, p1 A.h1, p2 B.h0, p3 B.h1
            if (p == 0 && stA) stage_half(A, m0, bufn, kA, 0);
            if (p == 1 && stA) stage_half(A, m0, bufn, kA, 1);
            if (p == 2 && stB) stage_half(B, n0, bufc + 32768, kB, 0);
            if (p == 3 && stB) stage_half(B, n0, bufc + 32768, kB, 1);

            __builtin_amdgcn_s_barrier();
            asm volatile("s_waitcnt lgkmcnt(0)" ::: "memory");
            __builtin_amdgcn_s_setprio(1);
            #pragma unroll
            for (int r = 0; r < 4; ++r)
                #pragma unroll
                for (int j = 0; j < 4; ++j)
                    acc[rg * 4 + r][j] = __builtin_amdgcn_mfma_f32_16x16x32_bf16(
                        af[r], bf[j][kk], acc[rg * 4 + r][j], 0, 0, 0);
            __builtin_amdgcn_s_setprio(0);
            if (p == 3) {
                if (t < 62)       asm volatile("s_waitcnt vmcnt(4)" ::: "memory");
                else if (t == 62) asm volatile("s_waitcnt vmcnt(0)" ::: "memory");
            }
            __builtin_amdgcn_s_barrier();
        }
    };

    for (int t2 = 0; t2 < 32; ++t2) {
        tile_body(buf0, buf1, 2 * t2);
        tile_body(buf1, buf0, 2 * t2 + 1);
    }

    // ---- epilogue ----
    const float wscale = scales[0];
    const float iscale = scales[1];

    float bv[4];
    #pragma unroll
    for (int j = 0; j < 4; ++j)
        bv[j] = bias[n0 + wn * 64 + j * 16 + col16] * iscale;

    #pragma unroll
    for (int i = 0; i < 8; ++i) {
        const int mbase = m0 + wm * 128 + i * 16 + quad * 4;
        #pragma unroll
        for (int j = 0; j < 4; ++j) {
            const int n = n0 + wn * 64 + j * 16 + col16;
            #pragma unroll
            for (int r = 0; r < 4; ++r)
                out[(size_t)(mbase + r) * N + n] = acc[i][j][r] * wscale + bv[j];
        }
    }
}

extern "C" void kernel_launch(void* const* d_in, const int* in_sizes, int n_in,
                              void* d_out, int out_size, void* d_ws, size_t ws_size,
                              hipStream_t stream) {
    const float* x    = (const float*)d_in[0];   // (2,2048,4096) fp32
    const float* w    = (const float*)d_in[1];   // (4096,4096) fp32
    const float* bias = (const float*)d_in[2];   // (4096,) fp32
    float* out = (float*)d_out;                  // (2,2048,4096) fp32

    char* ws = (char*)d_ws;
    float*  scales = (float*)ws;                       // 16 B
    double* px     = (double*)(ws + 256);              // 1024 doubles (8 KB)
    double* pw     = (double*)(ws + 256 + PB * 8);     // 1024 doubles (8 KB)
    unsigned short* xb = (unsigned short*)(ws + 16640);                      // 32 MB bf16 x
    unsigned short* qb = (unsigned short*)(ws + 16640 + (size_t)NELEM * 2);  // 32 MB bf16 qW

    prep_reduce<<<2 * PB, 256, 0, stream>>>(x, xb, w, px, pw);
    quantize_w<<<PB, 256, 0, stream>>>(w, qb, px, pw, scales);

    gemm_bt256<<<dim3(256), 512, 0, stream>>>(xb, qb, bias, scales, out);
}